// Round 4
// baseline (363.922 us; speedup 1.0000x reference)
//
#include <hip/hip_runtime.h>
#include <hip/hip_bf16.h>
#include <math.h>

// QwenStyleSparseMoEBlock: T=4096, D=1024, F=2048, E=4, top-2.
// R4: phase-split MFMA GEMMs (m201-style, conservative sync):
//   GEMM1: 256x256xBK64, 8 waves, 128KB dbuf LDS, gate+up interleaved B (Wcat),
//          4 phases/K-tile, T2 swizzle, T5 setprio, front-loaded prefetch,
//          tile-end vmcnt(0) drain (loads issued 2-3 phases earlier).
//   GEMM2: 128x256xBK64, 8 waves, 96KB dbuf LDS, 2 phases/K-tile, K=2048.
// Offsets pad-256. Scatter-combine via atomicAdd (2 contribs/elem, commutative).

typedef float  f32x4 __attribute__((ext_vector_type(4)));
typedef short  s16x8 __attribute__((ext_vector_type(8)));

__device__ __forceinline__ unsigned short f2bf(float f) {
  union { float f; unsigned int u; } v; v.f = f;
  return (unsigned short)((v.u + 0x7fffu + ((v.u >> 16) & 1u)) >> 16);  // RNE
}

__device__ __forceinline__ void glds16(const void* g, void* l) {
  __builtin_amdgcn_global_load_lds(
      (const __attribute__((address_space(1))) void*)g,
      (__attribute__((address_space(3))) void*)l, 16, 0, 0);
}

// st_16x32 swizzle on byte offsets (involution): spreads the 16-lane same-bank
// column of a [rows][64]bf16 tile. Read side.
__device__ __forceinline__ int swz(int o) { return o ^ (((o >> 9) & 1) << 5); }

// ---------------- routing ----------------
__global__ void k_routing(const float* __restrict__ x, const float* __restrict__ wg,
                          float* __restrict__ cw, int* __restrict__ idx,
                          int* __restrict__ cnt) {
  const int lane = threadIdx.x & 63;
  const int tok  = blockIdx.x * 4 + (threadIdx.x >> 6);
  const float* xr = x + (size_t)tok * 1024;
  float a0 = 0.f, a1 = 0.f, a2 = 0.f, a3 = 0.f;
#pragma unroll
  for (int j = 0; j < 16; ++j) {
    const int d = j * 64 + lane;
    const float xv = xr[d];
    a0 += xv * wg[0 * 1024 + d];
    a1 += xv * wg[1 * 1024 + d];
    a2 += xv * wg[2 * 1024 + d];
    a3 += xv * wg[3 * 1024 + d];
  }
#pragma unroll
  for (int off = 32; off; off >>= 1) {
    a0 += __shfl_xor(a0, off);
    a1 += __shfl_xor(a1, off);
    a2 += __shfl_xor(a2, off);
    a3 += __shfl_xor(a3, off);
  }
  if (lane == 0) {
    float l[4] = {a0, a1, a2, a3};
    const float m = fmaxf(fmaxf(l[0], l[1]), fmaxf(l[2], l[3]));
    float p[4];
#pragma unroll
    for (int e = 0; e < 4; ++e) p[e] = expf(l[e] - m);
    int i1 = 0; float b1 = p[0];
#pragma unroll
    for (int e = 1; e < 4; ++e) if (p[e] > b1) { b1 = p[e]; i1 = e; }
    int i2 = -1; float b2 = -1.f;
#pragma unroll
    for (int e = 0; e < 4; ++e) if (e != i1 && p[e] > b2) { b2 = p[e]; i2 = e; }
    const float inv = 1.f / (b1 + b2);
    float o[4] = {0.f, 0.f, 0.f, 0.f};
    o[i1] = b1 * inv; o[i2] = b2 * inv;
    *(float4*)(cw + (size_t)tok * 4) = make_float4(o[0], o[1], o[2], o[3]);
    const int p1 = atomicAdd(&cnt[i1], 1); idx[i1 * 4096 + p1] = tok;
    const int p2 = atomicAdd(&cnt[i2], 1); idx[i2 * 4096 + p2] = tok;
  }
}

// off[0..3]=row base (pad-256); off[4..8]=prefix of ceil256 (GEMM1 tiles);
// off[9..13]=prefix of ceil128 (GEMM2 tiles)
__global__ void k_offsets(const int* __restrict__ cnt, int* __restrict__ off) {
  if (threadIdx.x == 0 && blockIdx.x == 0) {
    int o = 0, q = 0, p = 0;
#pragma unroll
    for (int e = 0; e < 4; ++e) {
      off[e] = o; off[4 + e] = q; off[9 + e] = p;
      o += (cnt[e] + 255) & ~255;
      q += (cnt[e] + 255) >> 8;
      p += (cnt[e] + 127) >> 7;
    }
    off[8] = q; off[13] = p;
  }
}

// ---------------- X fp32 -> bf16 ----------------
__global__ void k_cvt_x(const float* __restrict__ in, unsigned short* __restrict__ out) {
  const int i = blockIdx.x * blockDim.x + threadIdx.x;
  const float4 v = ((const float4*)in)[i];
  ushort4 o;
  o.x = f2bf(v.x); o.y = f2bf(v.y); o.z = f2bf(v.z); o.w = f2bf(v.w);
  ((ushort4*)out)[i] = o;
}

// ---------------- weights -> transposed bf16; gate/up interleaved into Wcat ----------------
// grid (32,16,12), block (64,4). z<4: gate e=z; z<8: up e=z-4; z>=8: down e=z-8.
// Wcat row for f: gate -> (f>>4)*32 + (f&15); up -> +16.
__global__ void k_tcvt_all(const float* __restrict__ wgp, const float* __restrict__ wup,
                           const float* __restrict__ wdp,
                           unsigned short* __restrict__ Wcat,
                           unsigned short* __restrict__ Wdt) {
  __shared__ float t[64][65];
  const int z = blockIdx.z;
  const int tx = threadIdx.x, ty = threadIdx.y;
  const float* in; unsigned short* outp; int R, C, c0, r0, cat = 0, addup = 0;
  if (z < 8) {
    R = 1024; C = 2048;
    const int e = z & 3;
    in   = (z < 4 ? wgp : wup) + (size_t)e * 1024 * 2048;
    outp = Wcat + (size_t)e * 4096 * 1024;
    c0 = blockIdx.x * 64; r0 = blockIdx.y * 64;
    cat = 1; addup = (z >= 4) ? 16 : 0;
  } else {
    R = 2048; C = 1024;
    const int e = z & 3;
    in   = wdp + (size_t)e * 2048 * 1024;
    outp = Wdt + (size_t)e * 2048 * 1024;
    c0 = blockIdx.y * 64; r0 = blockIdx.x * 64;
  }
#pragma unroll
  for (int i = 0; i < 16; ++i) {
    const int r = i * 4 + ty;
    t[r][tx] = in[(size_t)(r0 + r) * C + c0 + tx];
  }
  __syncthreads();
#pragma unroll
  for (int i = 0; i < 16; ++i) {
    const int cc = i * 4 + ty;
    const int f = c0 + cc;
    const int orow = cat ? (((f >> 4) << 5) + (f & 15) + addup) : f;
    outp[(size_t)orow * R + r0 + tx] = f2bf(t[tx][cc]);
  }
}

// ---------------- GEMM1: H = gelu(Xg@Wg)*(Xg@Wu), 256x256, phase-split ----------------
__global__ __launch_bounds__(512, 2)
void k_gemm1(const unsigned short* __restrict__ Xb,
             const unsigned short* __restrict__ Wcat,
             unsigned short* __restrict__ H,
             const int* __restrict__ idx, const int* __restrict__ cnt,
             const int* __restrict__ off) {
  const int w0 = (blockIdx.x & 7) * 72 + (blockIdx.x >> 3);  // 576 = 8*72, bn-major
  const int bn = w0 / 36, mt = w0 % 36;
  const int* t1 = off + 4;
  if (mt >= t1[4]) return;
  const int e = (mt >= t1[1]) + (mt >= t1[2]) + (mt >= t1[3]);
  const int local = mt - t1[e];
  const int cn = cnt[e];
  const int lr0 = local * 256;
  const int hrow0 = off[e] + lr0;

  __shared__ __align__(16) unsigned short lds[2][2][256 * 64];  // 128 KiB

  const int tid = threadIdx.x;
  const int lane = tid & 63, wv = tid >> 6;
  const int wm = wv >> 2, wn = wv & 3;            // 2 x 4 waves
  const int l2 = lane ^ ((lane & 32) >> 4);       // store-side swizzle lane
  const int rsub = lane >> 3;
  const int gk = (l2 & 7) * 8;                    // swizzled source k-elems

  int tk[4];
#pragma unroll
  for (int i = 0; i < 4; ++i) {
    const int r = (wv * 4 + i) * 8 + rsub;
    tk[i] = idx[e * 4096 + min(lr0 + r, max(cn - 1, 0))];
  }
  const unsigned short* Wb = Wcat + (size_t)e * 4096 * 1024 + (size_t)(bn * 256) * 1024;

  f32x4 acc[8][4] = {};

  // prologue: stage tile 0 -> buf 0
#pragma unroll
  for (int i = 0; i < 4; ++i) {
    const int c = wv * 4 + i;
    glds16(Xb + (size_t)tk[i] * 1024 + gk, &lds[0][0][c * 512]);
    glds16(Wb + (size_t)(c * 8 + rsub) * 1024 + gk, &lds[0][1][c * 512]);
  }
  asm volatile("s_waitcnt vmcnt(0)\ns_barrier" ::: "memory");

  for (int kt = 0; kt < 16; ++kt) {
    const int cur = kt & 1;
    const unsigned short* Abuf = lds[cur][0];
    const unsigned short* Bbuf = lds[cur][1];
    unsigned short* An = lds[cur ^ 1][0];
    unsigned short* Bn = lds[cur ^ 1][1];
    const int kn = (kt + 1) * 64;
    const bool pf = (kt < 15);

    s16x8 bfr[4][2];
#pragma unroll
    for (int p = 0; p < 4; ++p) {
      s16x8 afr[2][2];
#pragma unroll
      for (int j = 0; j < 2; ++j) {
        const int row = wm * 128 + (p * 2 + j) * 16 + (lane & 15);
#pragma unroll
        for (int ks = 0; ks < 2; ++ks) {
          const int o = swz((row * 64 + ks * 32 + (lane >> 4) * 8) * 2);
          afr[j][ks] = *(const s16x8*)((const char*)Abuf + o);
        }
      }
      if (p == 0) {
#pragma unroll
        for (int ni = 0; ni < 4; ++ni) {
          const int row = wn * 64 + ni * 16 + (lane & 15);
#pragma unroll
          for (int ks = 0; ks < 2; ++ks) {
            const int o = swz((row * 64 + ks * 32 + (lane >> 4) * 8) * 2);
            bfr[ni][ks] = *(const s16x8*)((const char*)Bbuf + o);
          }
        }
        if (pf) {
#pragma unroll
          for (int i = 0; i < 4; ++i) {
            const int c = wv * 4 + i;
            glds16(Xb + (size_t)tk[i] * 1024 + kn + gk, &An[c * 512]);
          }
        }
      }
      if (p == 1 && pf) {
#pragma unroll
        for (int i = 0; i < 4; ++i) {
          const int c = wv * 4 + i;
          glds16(Wb + (size_t)(c * 8 + rsub) * 1024 + kn + gk, &Bn[c * 512]);
        }
      }
      asm volatile("s_barrier" ::: "memory");
      __builtin_amdgcn_s_setprio(1);
#pragma unroll
      for (int j = 0; j < 2; ++j) {
        const int mi = p * 2 + j;
#pragma unroll
        for (int ni = 0; ni < 4; ++ni) {
          acc[mi][ni] = __builtin_amdgcn_mfma_f32_16x16x32_bf16(afr[j][0], bfr[ni][0], acc[mi][ni], 0, 0, 0);
          acc[mi][ni] = __builtin_amdgcn_mfma_f32_16x16x32_bf16(afr[j][1], bfr[ni][1], acc[mi][ni], 0, 0, 0);
        }
      }
      __builtin_amdgcn_s_setprio(0);
      if (p < 3) { asm volatile("s_barrier" ::: "memory"); }
      else       { asm volatile("s_waitcnt vmcnt(0)\ns_barrier" ::: "memory"); }
    }
  }

  // epilogue: gelu(g)*u, interleaved pairs in-lane
  const int rbase = hrow0 + wm * 128;
#pragma unroll
  for (int mi = 0; mi < 8; ++mi)
#pragma unroll
    for (int q = 0; q < 2; ++q)
#pragma unroll
      for (int r = 0; r < 4; ++r) {
        const int row = rbase + mi * 16 + (lane >> 4) * 4 + r;
        const int col = bn * 128 + wn * 32 + q * 16 + (lane & 15);
        const float g = acc[mi][2 * q][r];
        const float u = acc[mi][2 * q + 1][r];
        const float h = 0.5f * g * (1.0f + erff(g * 0.70710678118654752f)) * u;
        H[(size_t)row * 2048 + col] = f2bf(h);
      }
}

// ---------------- GEMM2: out += cw * (H_e @ Wd_e), 128x256, phase-split ----------------
__global__ __launch_bounds__(512, 2)
void k_gemm2(const unsigned short* __restrict__ H,
             const unsigned short* __restrict__ Wdt,
             const float* __restrict__ cw,
             const int* __restrict__ idx, const int* __restrict__ cnt,
             const int* __restrict__ off, float* __restrict__ out) {
  const int w0 = (blockIdx.x & 7) * 34 + (blockIdx.x >> 3);  // 272 = 8*34, mt-major
  const int mt = w0 >> 2, bn = w0 & 3;
  const int* t2 = off + 9;
  if (mt >= t2[4]) return;
  const int e = (mt >= t2[1]) + (mt >= t2[2]) + (mt >= t2[3]);
  const int local = mt - t2[e];
  const int cn = cnt[e];
  const int lr0 = local * 128;
  const int hrow0 = off[e] + lr0;

  __shared__ __align__(16) unsigned short lds[2][(128 + 256) * 64];  // 96 KiB

  const int tid = threadIdx.x;
  const int lane = tid & 63, wv = tid >> 6;
  const int wm = wv >> 2, wn = wv & 3;
  const int l2 = lane ^ ((lane & 32) >> 4);
  const int rsub = lane >> 3;
  const int gk = (l2 & 7) * 8;

  const unsigned short* Ha = H + (size_t)hrow0 * 2048;
  const unsigned short* Wd = Wdt + (size_t)e * 1024 * 2048 + (size_t)(bn * 256) * 2048;

  f32x4 acc[4][4] = {};

  // prologue
#pragma unroll
  for (int i = 0; i < 2; ++i) {
    const int c = wv * 2 + i;
    glds16(Ha + (size_t)(c * 8 + rsub) * 2048 + gk, &lds[0][c * 512]);
  }
#pragma unroll
  for (int i = 0; i < 4; ++i) {
    const int c = wv * 4 + i;
    glds16(Wd + (size_t)(c * 8 + rsub) * 2048 + gk, &lds[0][128 * 64 + c * 512]);
  }
  asm volatile("s_waitcnt vmcnt(0)\ns_barrier" ::: "memory");

  for (int kt = 0; kt < 32; ++kt) {
    const int cur = kt & 1;
    const unsigned short* Abuf = &lds[cur][0];
    const unsigned short* Bbuf = &lds[cur][128 * 64];
    unsigned short* An = &lds[cur ^ 1][0];
    unsigned short* Bn = &lds[cur ^ 1][128 * 64];
    const int kn = (kt + 1) * 64;
    const bool pf = (kt < 31);

    s16x8 bfr[4][2];
#pragma unroll
    for (int p = 0; p < 2; ++p) {
      s16x8 afr[2][2];
#pragma unroll
      for (int j = 0; j < 2; ++j) {
        const int row = wm * 64 + (p * 2 + j) * 16 + (lane & 15);
#pragma unroll
        for (int ks = 0; ks < 2; ++ks) {
          const int o = swz((row * 64 + ks * 32 + (lane >> 4) * 8) * 2);
          afr[j][ks] = *(const s16x8*)((const char*)Abuf + o);
        }
      }
      if (p == 0) {
#pragma unroll
        for (int ni = 0; ni < 4; ++ni) {
          const int row = wn * 64 + ni * 16 + (lane & 15);
#pragma unroll
          for (int ks = 0; ks < 2; ++ks) {
            const int o = swz((row * 64 + ks * 32 + (lane >> 4) * 8) * 2);
            bfr[ni][ks] = *(const s16x8*)((const char*)Bbuf + o);
          }
        }
        if (pf) {
#pragma unroll
          for (int i = 0; i < 4; ++i) {
            const int c = wv * 4 + i;
            glds16(Wd + (size_t)(c * 8 + rsub) * 2048 + kn + gk, &Bn[c * 512]);
          }
        }
      } else if (pf) {
#pragma unroll
        for (int i = 0; i < 2; ++i) {
          const int c = wv * 2 + i;
          glds16(Ha + (size_t)(c * 8 + rsub) * 2048 + kn + gk, &An[c * 512]);
        }
      }
      asm volatile("s_barrier" ::: "memory");
      __builtin_amdgcn_s_setprio(1);
#pragma unroll
      for (int j = 0; j < 2; ++j) {
        const int mi = p * 2 + j;
#pragma unroll
        for (int ni = 0; ni < 4; ++ni) {
          acc[mi][ni] = __builtin_amdgcn_mfma_f32_16x16x32_bf16(afr[j][0], bfr[ni][0], acc[mi][ni], 0, 0, 0);
          acc[mi][ni] = __builtin_amdgcn_mfma_f32_16x16x32_bf16(afr[j][1], bfr[ni][1], acc[mi][ni], 0, 0, 0);
        }
      }
      __builtin_amdgcn_s_setprio(0);
      if (p == 0) { asm volatile("s_barrier" ::: "memory"); }
      else        { asm volatile("s_waitcnt vmcnt(0)\ns_barrier" ::: "memory"); }
    }
  }

  // epilogue: weighted atomic scatter
#pragma unroll
  for (int mi = 0; mi < 4; ++mi)
#pragma unroll
    for (int r = 0; r < 4; ++r) {
      const int lr = lr0 + wm * 64 + mi * 16 + (lane >> 4) * 4 + r;
      if (lr < cn) {
        const int tok = idx[e * 4096 + lr];
        const float wgt = cw[(size_t)tok * 4 + e];
        float* orow = out + (size_t)tok * 1024 + bn * 256 + wn * 64 + (lane & 15);
#pragma unroll
        for (int ni = 0; ni < 4; ++ni)
          atomicAdd(orow + ni * 16, acc[mi][ni][r] * wgt);
      }
    }
}

extern "C" void kernel_launch(void* const* d_in, const int* in_sizes, int n_in,
                              void* d_out, int out_size, void* d_ws, size_t ws_size,
                              hipStream_t stream) {
  const float* x     = (const float*)d_in[0];
  const float* wgate = (const float*)d_in[1];
  const float* wgp   = (const float*)d_in[2];
  const float* wup   = (const float*)d_in[3];
  const float* wdp   = (const float*)d_in[4];
  float* out = (float*)d_out;

  char* ws = (char*)d_ws;
  float* cw            = (float*)ws;                       // 64 KB
  int*   idx           = (int*)(ws + 65536);               // 64 KB
  int*   cnt           = (int*)(ws + 131072);              // 16 B
  int*   off           = (int*)(ws + 131136);              // 56 B
  unsigned short* Xb   = (unsigned short*)(ws + 131584);   // 8 MB
  unsigned short* Wcat = Xb   + (size_t)4096 * 1024;       // 32 MB
  unsigned short* Wdt  = Wcat + (size_t)4 * 4096 * 1024;   // 16 MB
  unsigned short* H    = Wdt  + (size_t)4 * 1024 * 2048;   // 9216 x 2048 bf16 = 37.75 MB
  // total ~92.1 MiB

  hipMemsetAsync(cnt, 0, 16, stream);
  hipMemsetAsync(out, 0, (size_t)4096 * 1024 * 4, stream);
  k_routing<<<1024, 256, 0, stream>>>(x, wgate, cw, idx, cnt);
  k_offsets<<<1, 64, 0, stream>>>(cnt, off);
  k_cvt_x<<<4096, 256, 0, stream>>>(x, Xb);
  k_tcvt_all<<<dim3(32, 16, 12), dim3(64, 4), 0, stream>>>(wgp, wup, wdp, Wcat, Wdt);

  k_gemm1<<<576, 512, 0, stream>>>(Xb, Wcat, H, idx, cnt, off);
  k_gemm2<<<272, 512, 0, stream>>>(H, Wdt, cw, idx, cnt, off, out);
}